// Round 1
// baseline (914.093 us; speedup 1.0000x reference)
//
#include <hip/hip_runtime.h>
#include <cmath>

#define BATCH 4
#define SEQ 2048
#define DM 512
#define NH 8
#define DH 64
#define WINDOW 256

// ---------------- GEMM: C[M,N] = A[M,K] @ W[N,K]^T (fp32 vector ALU) ----------------
// blockIdx.z selects among up to 3 (W, C) pairs so QKV runs as one launch.
#define GM 64
#define GN 64
#define GK 16

__global__ __launch_bounds__(256) void gemm_xwt(
    const float* __restrict__ A,
    const float* __restrict__ W0, const float* __restrict__ W1, const float* __restrict__ W2,
    float* __restrict__ C0, float* __restrict__ C1, float* __restrict__ C2,
    int M, int N, int K)
{
    const float* W = (blockIdx.z == 0) ? W0 : (blockIdx.z == 1) ? W1 : W2;
    float*       C = (blockIdx.z == 0) ? C0 : (blockIdx.z == 1) ? C1 : C2;

    __shared__ float As[GK][GM + 4];   // [k][m], stride 68 floats: float4-aligned, 2-way max on write
    __shared__ float Bs[GK][GN + 4];

    const int tid = threadIdx.x;
    const int m0 = blockIdx.x * GM;
    const int n0 = blockIdx.y * GN;
    const int lr = tid >> 2;          // load row 0..63
    const int lc = (tid & 3) << 2;    // load col 0,4,8,12
    const int tm = (tid >> 4) << 2;   // thread tile 4x4
    const int tn = (tid & 15) << 2;

    const float* Ap = A + (size_t)(m0 + lr) * K + lc;
    const float* Wp = W + (size_t)(n0 + lr) * K + lc;

    float acc[4][4] = {};

    for (int k0 = 0; k0 < K; k0 += GK) {
        float4 av = *reinterpret_cast<const float4*>(Ap + k0);
        float4 wv = *reinterpret_cast<const float4*>(Wp + k0);
        __syncthreads();   // previous iteration's readers done
        As[lc + 0][lr] = av.x; As[lc + 1][lr] = av.y;
        As[lc + 2][lr] = av.z; As[lc + 3][lr] = av.w;
        Bs[lc + 0][lr] = wv.x; Bs[lc + 1][lr] = wv.y;
        Bs[lc + 2][lr] = wv.z; Bs[lc + 3][lr] = wv.w;
        __syncthreads();
#pragma unroll
        for (int kk = 0; kk < GK; ++kk) {
            float4 a4 = *reinterpret_cast<const float4*>(&As[kk][tm]);
            float4 b4 = *reinterpret_cast<const float4*>(&Bs[kk][tn]);
            float a[4] = {a4.x, a4.y, a4.z, a4.w};
            float b[4] = {b4.x, b4.y, b4.z, b4.w};
#pragma unroll
            for (int i = 0; i < 4; ++i)
#pragma unroll
                for (int j = 0; j < 4; ++j)
                    acc[i][j] = fmaf(a[i], b[j], acc[i][j]);
        }
    }

#pragma unroll
    for (int i = 0; i < 4; ++i) {
        float4 r = make_float4(acc[i][0], acc[i][1], acc[i][2], acc[i][3]);
        *reinterpret_cast<float4*>(&C[(size_t)(m0 + tm + i) * N + n0 + tn]) = r;
    }
}

// ---------------- Attention (flash-style, fp32) ----------------
// Block = 256 threads handles 64 queries of one (b,h). Thread (ql=tid>>2, qd=tid&3):
//  - scores phase: keys m0 + 4j + qd (j=0..15)  [interleave -> conflict-free Ks reads]
//  - PV phase:     output dims qd*16 .. qd*16+15
#define QB 64
#define KB 64
#define KS 68   // padded LDS stride (floats)

__global__ __launch_bounds__(256) void attn_kernel(
    const float* __restrict__ Q, const float* __restrict__ K,
    const float* __restrict__ V, const int* __restrict__ amask,
    float* __restrict__ AO)
{
    __shared__ float Ks[KB][KS];
    __shared__ float Vs[KB][KS];
    __shared__ float Ps[QB][KS];
    __shared__ int   Ms[KB];

    const int tid = threadIdx.x;
    const int qb  = blockIdx.x;
    const int bh  = blockIdx.y;
    const int b = bh >> 3;
    const int h = bh & 7;
    const int n0 = qb * QB;

    const int ql = tid >> 2;   // query within block
    const int qd = tid & 3;    // quad
    const int n  = n0 + ql;

    // q row in registers (16 float4 = 64 VGPR)
    float4 qreg[16];
    {
        const float* qrow = Q + (size_t)(b * SEQ + n) * DM + h * DH;
#pragma unroll
        for (int c = 0; c < 16; ++c)
            qreg[c] = *reinterpret_cast<const float4*>(qrow + 4 * c);
    }

    float o[16];
#pragma unroll
    for (int d = 0; d < 16; ++d) o[d] = 0.f;
    float m_run = -INFINITY, l_run = 0.f;

    const int m_last = min(n0 + QB - 1 + WINDOW - 1, SEQ - 1);
    const int ntiles = m_last / KB + 1;

    for (int t = 0; t < ntiles; ++t) {
        const int m0 = t * KB;
        __syncthreads();   // previous tile's PV readers done before overwrite
        {
            const int r  = tid >> 2;          // key row
            const int c4 = (tid & 3) * 16;    // 16 floats per thread
            const float* kp = K + (size_t)(b * SEQ + m0 + r) * DM + h * DH + c4;
            const float* vp = V + (size_t)(b * SEQ + m0 + r) * DM + h * DH + c4;
#pragma unroll
            for (int c = 0; c < 4; ++c) {
                *reinterpret_cast<float4*>(&Ks[r][c4 + 4 * c]) =
                    *reinterpret_cast<const float4*>(kp + 4 * c);
                *reinterpret_cast<float4*>(&Vs[r][c4 + 4 * c]) =
                    *reinterpret_cast<const float4*>(vp + 4 * c);
            }
            if (tid < KB) Ms[tid] = amask[(size_t)b * SEQ + m0 + tid];
        }
        __syncthreads();

        // ---- scores for 16 keys ----
        float p[16];
        float tmax = -INFINITY;
#pragma unroll
        for (int j = 0; j < 16; ++j) {
            const int kl = 4 * j + qd;
            const int m  = m0 + kl;
            float s = 0.f;
#pragma unroll
            for (int c = 0; c < 16; ++c) {
                float4 kv = *reinterpret_cast<const float4*>(&Ks[kl][4 * c]);
                s = fmaf(qreg[c].x, kv.x, s);
                s = fmaf(qreg[c].y, kv.y, s);
                s = fmaf(qreg[c].z, kv.z, s);
                s = fmaf(qreg[c].w, kv.w, s);
            }
            s *= 0.125f;   // 1/sqrt(64)
            const bool ok = ((m - n) <= (WINDOW - 1)) && (Ms[kl] != 0);
            s = ok ? s : -INFINITY;
            p[j] = s;
            tmax = fmaxf(tmax, s);
        }
        // max over the 4-lane quad group (lanes differ in bits 0..1)
        tmax = fmaxf(tmax, __shfl_xor(tmax, 1));
        tmax = fmaxf(tmax, __shfl_xor(tmax, 2));

        const float m_new = fmaxf(m_run, tmax);
        const float scale = __expf(m_run - m_new);   // first tile: exp(-inf)=0
        float lsum = 0.f;
#pragma unroll
        for (int j = 0; j < 16; ++j) {
            const float e = __expf(p[j] - m_new);    // masked: exp(-inf)=0
            p[j] = e;
            lsum += e;
        }
        lsum += __shfl_xor(lsum, 1);
        lsum += __shfl_xor(lsum, 2);
        l_run = l_run * scale + lsum;
        m_run = m_new;
#pragma unroll
        for (int d = 0; d < 16; ++d) o[d] *= scale;
#pragma unroll
        for (int j = 0; j < 16; ++j) Ps[ql][4 * j + qd] = p[j];
        __syncthreads();

        // ---- PV: o[qd*16 + d] += sum_k P[ql][k] * V[k][qd*16 + d] ----
#pragma unroll 8
        for (int kl = 0; kl < KB; ++kl) {
            const float pv = Ps[ql][kl];
#pragma unroll
            for (int c = 0; c < 4; ++c) {
                float4 vv = *reinterpret_cast<const float4*>(&Vs[kl][qd * 16 + 4 * c]);
                o[4 * c + 0] = fmaf(pv, vv.x, o[4 * c + 0]);
                o[4 * c + 1] = fmaf(pv, vv.y, o[4 * c + 1]);
                o[4 * c + 2] = fmaf(pv, vv.z, o[4 * c + 2]);
                o[4 * c + 3] = fmaf(pv, vv.w, o[4 * c + 3]);
            }
        }
    }

    const float inv_l = 1.0f / l_run;
    float* orow = AO + (size_t)(b * SEQ + n) * DM + h * DH + qd * 16;
#pragma unroll
    for (int c = 0; c < 4; ++c) {
        float4 r = make_float4(o[4 * c + 0] * inv_l, o[4 * c + 1] * inv_l,
                               o[4 * c + 2] * inv_l, o[4 * c + 3] * inv_l);
        *reinterpret_cast<float4*>(&orow[4 * c]) = r;
    }
}

extern "C" void kernel_launch(void* const* d_in, const int* in_sizes, int n_in,
                              void* d_out, int out_size, void* d_ws, size_t ws_size,
                              hipStream_t stream) {
    const float* hs    = (const float*)d_in[0];
    const int*   amask = (const int*)  d_in[1];
    const float* Wq    = (const float*)d_in[2];
    const float* Wk    = (const float*)d_in[3];
    const float* Wv    = (const float*)d_in[4];
    const float* Wo    = (const float*)d_in[5];
    float* out = (float*)d_out;

    const size_t tok = (size_t)BATCH * SEQ * DM;   // 4*2048*512 = 4,194,304 floats
    float* Qb = (float*)d_ws;
    float* Kb = Qb + tok;
    float* Vb = Kb + tok;
    float* AO = Vb + tok;   // total 64 MB fp32

    const int M = BATCH * SEQ;   // 8192

    dim3 gQKV(M / GM, DM / GN, 3);
    gemm_xwt<<<gQKV, 256, 0, stream>>>(hs, Wq, Wk, Wv, Qb, Kb, Vb, M, DM, DM);

    dim3 gAttn(SEQ / QB, BATCH * NH);
    attn_kernel<<<gAttn, 256, 0, stream>>>(Qb, Kb, Vb, amask, AO);

    dim3 gOut(M / GM, DM / GN, 1);
    gemm_xwt<<<gOut, 256, 0, stream>>>(AO, Wo, Wo, Wo, out, out, out, M, DM, DM);
}

// Round 2
// 236.010 us; speedup vs baseline: 3.8731x; 3.8731x over previous
//
#include <hip/hip_runtime.h>

#define BATCH 4
#define SEQ 2048
#define DM 512
#define NH 8
#define DH 64
#define WINDOW 256
#define NEGINF (-1e30f)

typedef __attribute__((ext_vector_type(8))) short bf16x8;
typedef __attribute__((ext_vector_type(4))) float f32x4;
typedef __attribute__((ext_vector_type(4))) unsigned short u16x4;

__device__ __forceinline__ unsigned short f2bf(float f) {
    union { float f; unsigned int u; } v; v.f = f;
    unsigned int u = v.u;
    u += 0x7FFFu + ((u >> 16) & 1u);   // round-to-nearest-even
    return (unsigned short)(u >> 16);
}

// 64-col bf16 tiles: 128-byte rows, XOR swizzle on bits 4-6 (verified G4 fix)
__device__ __forceinline__ int swz128(int row, int byte_in_row) {
    return row * 128 + (byte_in_row ^ ((row & 7) << 4));
}

#define MFMA(a, b, c) __builtin_amdgcn_mfma_f32_16x16x32_bf16(a, b, c, 0, 0, 0)

// ---------------------------------------------------------------------------
// GEMM: C[M,N] = A[M,K] @ W[N,K]^T.  A fp32 or bf16 (template), W fp32,
// C bf16 or fp32 (template). 128x128 tile, BK=64, 4 waves, bf16 MFMA.
// blockIdx.z picks among 3 (W,C) pairs so QKV is one dispatch.
// ---------------------------------------------------------------------------
template<bool A_BF16, bool OUT_BF16>
__global__ __launch_bounds__(256) void gemm_mfma(
    const void* __restrict__ Av,
    const float* __restrict__ W0, const float* __restrict__ W1, const float* __restrict__ W2,
    void* __restrict__ C0, void* __restrict__ C1, void* __restrict__ C2,
    int M, int N, int K)
{
    const float* W = (blockIdx.z == 0) ? W0 : (blockIdx.z == 1) ? W1 : W2;
    void*        C = (blockIdx.z == 0) ? C0 : (blockIdx.z == 1) ? C1 : C2;

    __shared__ unsigned short As[128 * 64];   // 16 KB, swizzled
    __shared__ unsigned short Ws[128 * 64];   // 16 KB, swizzled

    const int tid  = threadIdx.x;
    const int m0   = blockIdx.x * 128;
    const int n0   = blockIdx.y * 128;
    const int lane = tid & 63;
    const int wv   = tid >> 6;
    const int wm   = wv >> 1, wn = wv & 1;
    const int g    = lane >> 4;        // 0..3 (k-group)
    const int lr   = lane & 15;        // row/col within fragment

    const int r0   = tid >> 2;         // staging row 0..63
    const int cgrp = tid & 3;          // staging col group (16 elems each)

    f32x4 acc[4][4];
#pragma unroll
    for (int i = 0; i < 4; ++i)
#pragma unroll
        for (int j = 0; j < 4; ++j) {
            f32x4 z = {0.f, 0.f, 0.f, 0.f};
            acc[i][j] = z;
        }

    for (int k0 = 0; k0 < K; k0 += 64) {
        __syncthreads();
        // ---- stage A ----
        if constexpr (A_BF16) {
            const unsigned short* A = (const unsigned short*)Av;
#pragma unroll
            for (int rr = 0; rr < 2; ++rr) {
                const int r = r0 + 64 * rr;
                const unsigned short* src = A + (size_t)(m0 + r) * K + k0 + cgrp * 16;
                uint4 v0 = *reinterpret_cast<const uint4*>(src);
                uint4 v1 = *reinterpret_cast<const uint4*>(src + 8);
                *reinterpret_cast<uint4*>((char*)As + swz128(r, cgrp * 32))      = v0;
                *reinterpret_cast<uint4*>((char*)As + swz128(r, cgrp * 32 + 16)) = v1;
            }
        } else {
            const float* A = (const float*)Av;
#pragma unroll
            for (int rr = 0; rr < 2; ++rr) {
                const int r = r0 + 64 * rr;
                const float* src = A + (size_t)(m0 + r) * K + k0 + cgrp * 16;
#pragma unroll
                for (int c = 0; c < 4; ++c) {
                    float4 v = *reinterpret_cast<const float4*>(src + 4 * c);
                    u16x4 b; b.x = f2bf(v.x); b.y = f2bf(v.y); b.z = f2bf(v.z); b.w = f2bf(v.w);
                    *reinterpret_cast<u16x4*>((char*)As + swz128(r, cgrp * 32 + 8 * c)) = b;
                }
            }
        }
        // ---- stage W (always fp32 in) ----
        {
#pragma unroll
            for (int rr = 0; rr < 2; ++rr) {
                const int r = r0 + 64 * rr;
                const float* src = W + (size_t)(n0 + r) * K + k0 + cgrp * 16;
#pragma unroll
                for (int c = 0; c < 4; ++c) {
                    float4 v = *reinterpret_cast<const float4*>(src + 4 * c);
                    u16x4 b; b.x = f2bf(v.x); b.y = f2bf(v.y); b.z = f2bf(v.z); b.w = f2bf(v.w);
                    *reinterpret_cast<u16x4*>((char*)Ws + swz128(r, cgrp * 32 + 8 * c)) = b;
                }
            }
        }
        __syncthreads();
        // ---- compute: 2 k-subtiles of 32, 16 MFMA each ----
#pragma unroll
        for (int ks = 0; ks < 2; ++ks) {
            bf16x8 af[4], bfr[4];
#pragma unroll
            for (int i = 0; i < 4; ++i)
                af[i] = *reinterpret_cast<const bf16x8*>(
                    (char*)As + swz128(64 * wm + 16 * i + lr, 64 * ks + 16 * g));
#pragma unroll
            for (int j = 0; j < 4; ++j)
                bfr[j] = *reinterpret_cast<const bf16x8*>(
                    (char*)Ws + swz128(64 * wn + 16 * j + lr, 64 * ks + 16 * g));
#pragma unroll
            for (int i = 0; i < 4; ++i)
#pragma unroll
                for (int j = 0; j < 4; ++j)
                    acc[i][j] = MFMA(af[i], bfr[j], acc[i][j]);
        }
    }

    // ---- epilogue: C/D layout col=lane&15, row=(lane>>4)*4+r (m89-verified) ----
#pragma unroll
    for (int i = 0; i < 4; ++i)
#pragma unroll
        for (int j = 0; j < 4; ++j) {
            const int col = n0 + 64 * wn + 16 * j + lr;
#pragma unroll
            for (int r = 0; r < 4; ++r) {
                const int row = m0 + 64 * wm + 16 * i + 4 * g + r;
                if constexpr (OUT_BF16)
                    ((unsigned short*)C)[(size_t)row * N + col] = f2bf(acc[i][j][r]);
                else
                    ((float*)C)[(size_t)row * N + col] = acc[i][j][r];
            }
        }
}

// ---------------------------------------------------------------------------
// Flash attention, bf16 MFMA. Block = 256 threads = 4 waves; 64 queries of one
// (b,h); wave w owns q rows 16w..16w+15. KV tile = 64. Online softmax in the
// accumulator layout; P staged via LDS (wave-local, no extra barrier).
// ---------------------------------------------------------------------------
__global__ __launch_bounds__(256) void attn_mfma(
    const unsigned short* __restrict__ Q, const unsigned short* __restrict__ K,
    const unsigned short* __restrict__ V, const int* __restrict__ amask,
    unsigned short* __restrict__ AO)
{
    __shared__ unsigned short Ks[64 * 64];   // [kv][d]  swizzled
    __shared__ unsigned short Vt[64 * 64];   // [d][kv]  swizzled (transposed)
    __shared__ unsigned short Ps[64 * 64];   // [q][kv]  swizzled
    __shared__ int Ms[64];

    const int tid = threadIdx.x;
    const int n0  = blockIdx.x * 64;
    const int bh  = blockIdx.y;
    const int b = bh >> 3, h = bh & 7;

    const int lane = tid & 63;
    const int wv   = tid >> 6;
    const int g    = lane >> 4;
    const int lr   = lane & 15;

    // Q fragments in registers: rows n0+16wv+lr, k-groups 8g
    bf16x8 qf[2];
    {
        const unsigned short* qp =
            Q + (size_t)(b * SEQ + n0 + 16 * wv + lr) * DM + h * DH + 8 * g;
        qf[0] = *reinterpret_cast<const bf16x8*>(qp);
        qf[1] = *reinterpret_cast<const bf16x8*>(qp + 32);
    }

    f32x4 o[4];
#pragma unroll
    for (int j = 0; j < 4; ++j) { f32x4 z = {0.f,0.f,0.f,0.f}; o[j] = z; }
    float m_run[4] = {NEGINF, NEGINF, NEGINF, NEGINF};
    float l_run[4] = {0.f, 0.f, 0.f, 0.f};

    int ntiles = (n0 + 63 + WINDOW - 1) / 64 + 1;
    if (ntiles > SEQ / 64) ntiles = SEQ / 64;

    const int r_st  = tid & 63;   // staging kv row
    const int half  = tid >> 6;   // staging 16-col group

    for (int t = 0; t < ntiles; ++t) {
        const int kv0 = t * 64;
        __syncthreads();
        // ---- stage K tile and transposed V tile ----
        {
            const unsigned short* kp =
                K + (size_t)(b * SEQ + kv0 + r_st) * DM + h * DH + 16 * half;
            uint4 k0 = *reinterpret_cast<const uint4*>(kp);
            uint4 k1 = *reinterpret_cast<const uint4*>(kp + 8);
            *reinterpret_cast<uint4*>((char*)Ks + swz128(r_st, 32 * half))      = k0;
            *reinterpret_cast<uint4*>((char*)Ks + swz128(r_st, 32 * half + 16)) = k1;

            const unsigned short* vp =
                V + (size_t)(b * SEQ + kv0 + r_st) * DM + h * DH + 16 * half;
            uint4 w0 = *reinterpret_cast<const uint4*>(vp);
            uint4 w1 = *reinterpret_cast<const uint4*>(vp + 8);
            unsigned short tmp[16];
            *reinterpret_cast<uint4*>(tmp)     = w0;
            *reinterpret_cast<uint4*>(tmp + 8) = w1;
#pragma unroll
            for (int j = 0; j < 16; ++j) {
                const int d = 16 * half + j;
                *(unsigned short*)((char*)Vt + swz128(d, 2 * r_st)) = tmp[j];
            }
            if (tid < 64) Ms[tid] = amask[(size_t)b * SEQ + kv0 + tid];
        }
        __syncthreads();

        // ---- S = Q K^T for this wave's 16 rows x 64 kv ----
        f32x4 s[4];
#pragma unroll
        for (int f = 0; f < 4; ++f) {
            bf16x8 kf0 = *reinterpret_cast<const bf16x8*>(
                (char*)Ks + swz128(16 * f + lr, 16 * g));
            bf16x8 kf1 = *reinterpret_cast<const bf16x8*>(
                (char*)Ks + swz128(16 * f + lr, 64 + 16 * g));
            f32x4 z = {0.f,0.f,0.f,0.f};
            z = MFMA(qf[0], kf0, z);
            z = MFMA(qf[1], kf1, z);
            s[f] = z;
        }

        // ---- scale + mask + online softmax (accumulator layout) ----
        float tm[4] = {NEGINF, NEGINF, NEGINF, NEGINF};
#pragma unroll
        for (int f = 0; f < 4; ++f)
#pragma unroll
            for (int r = 0; r < 4; ++r) {
                const int kv = kv0 + 16 * f + lr;
                const int q  = n0 + 16 * wv + 4 * g + r;
                float sv = s[f][r] * 0.125f;
                const bool ok = ((kv - q) <= (WINDOW - 1)) && (Ms[16 * f + lr] != 0);
                sv = ok ? sv : NEGINF;
                s[f][r] = sv;
                tm[r] = fmaxf(tm[r], sv);
            }
#pragma unroll
        for (int r = 0; r < 4; ++r) {
            tm[r] = fmaxf(tm[r], __shfl_xor(tm[r], 1));
            tm[r] = fmaxf(tm[r], __shfl_xor(tm[r], 2));
            tm[r] = fmaxf(tm[r], __shfl_xor(tm[r], 4));
            tm[r] = fmaxf(tm[r], __shfl_xor(tm[r], 8));
        }
        float sc[4];
#pragma unroll
        for (int r = 0; r < 4; ++r) {
            const float mn = fmaxf(m_run[r], tm[r]);
            sc[r] = __expf(m_run[r] - mn);
            m_run[r] = mn;
        }
        float ls[4] = {0.f, 0.f, 0.f, 0.f};
#pragma unroll
        for (int f = 0; f < 4; ++f)
#pragma unroll
            for (int r = 0; r < 4; ++r) {
                const float p = __expf(s[f][r] - m_run[r]);
                s[f][r] = p;
                ls[r] += p;
            }
#pragma unroll
        for (int r = 0; r < 4; ++r) {
            ls[r] += __shfl_xor(ls[r], 1);
            ls[r] += __shfl_xor(ls[r], 2);
            ls[r] += __shfl_xor(ls[r], 4);
            ls[r] += __shfl_xor(ls[r], 8);
            l_run[r] = l_run[r] * sc[r] + ls[r];
        }
#pragma unroll
        for (int j = 0; j < 4; ++j)
#pragma unroll
            for (int r = 0; r < 4; ++r) o[j][r] *= sc[r];

        // ---- P -> LDS (bf16), wave-local rows ----
#pragma unroll
        for (int f = 0; f < 4; ++f)
#pragma unroll
            for (int r = 0; r < 4; ++r) {
                const int row = 16 * wv + 4 * g + r;
                *(unsigned short*)((char*)Ps + swz128(row, 2 * (16 * f + lr))) =
                    f2bf(s[f][r]);
            }

        // ---- O += P V  (A = P rows of this wave, B = Vt rows = d) ----
        bf16x8 pf0 = *reinterpret_cast<const bf16x8*>(
            (char*)Ps + swz128(16 * wv + lr, 16 * g));
        bf16x8 pf1 = *reinterpret_cast<const bf16x8*>(
            (char*)Ps + swz128(16 * wv + lr, 64 + 16 * g));
#pragma unroll
        for (int j = 0; j < 4; ++j) {
            bf16x8 vf0 = *reinterpret_cast<const bf16x8*>(
                (char*)Vt + swz128(16 * j + lr, 16 * g));
            bf16x8 vf1 = *reinterpret_cast<const bf16x8*>(
                (char*)Vt + swz128(16 * j + lr, 64 + 16 * g));
            o[j] = MFMA(pf0, vf0, o[j]);
            o[j] = MFMA(pf1, vf1, o[j]);
        }
    }

    // ---- normalize + store AO (bf16) ----
    float inv[4];
#pragma unroll
    for (int r = 0; r < 4; ++r) inv[r] = 1.f / l_run[r];
#pragma unroll
    for (int j = 0; j < 4; ++j)
#pragma unroll
        for (int r = 0; r < 4; ++r) {
            const int row = n0 + 16 * wv + 4 * g + r;
            const int col = h * DH + 16 * j + lr;
            AO[(size_t)(b * SEQ + row) * DM + col] = f2bf(o[j][r] * inv[r]);
        }
}

extern "C" void kernel_launch(void* const* d_in, const int* in_sizes, int n_in,
                              void* d_out, int out_size, void* d_ws, size_t ws_size,
                              hipStream_t stream) {
    const float* hs    = (const float*)d_in[0];
    const int*   amask = (const int*)  d_in[1];
    const float* Wq    = (const float*)d_in[2];
    const float* Wk    = (const float*)d_in[3];
    const float* Wv    = (const float*)d_in[4];
    const float* Wo    = (const float*)d_in[5];
    float* out = (float*)d_out;

    const size_t tok = (size_t)BATCH * SEQ * DM;          // 4.2M elems
    unsigned short* Qb  = (unsigned short*)d_ws;          // bf16 buffers, 8 MB each
    unsigned short* Kb  = Qb + tok;
    unsigned short* Vb  = Kb + tok;
    unsigned short* AOb = Vb + tok;

    const int M = BATCH * SEQ;   // 8192

    dim3 gQKV(M / 128, DM / 128, 3);
    gemm_mfma<false, true><<<gQKV, 256, 0, stream>>>(
        hs, Wq, Wk, Wv, Qb, Kb, Vb, M, DM, DM);

    dim3 gAttn(SEQ / 64, BATCH * NH);
    attn_mfma<<<gAttn, 256, 0, stream>>>(Qb, Kb, Vb, amask, AOb);

    dim3 gOut(M / 128, DM / 128, 1);
    gemm_mfma<true, false><<<gOut, 256, 0, stream>>>(
        AOb, Wo, Wo, Wo, out, out, out, M, DM, DM);
}

// Round 3
// 224.001 us; speedup vs baseline: 4.0808x; 1.0536x over previous
//
#include <hip/hip_runtime.h>
#include <hip/hip_bf16.h>

#define BATCH 4
#define SEQ 2048
#define DM 512
#define NH 8
#define DH 64
#define WINDOW 256
#define NEGINF (-1e30f)

typedef __attribute__((ext_vector_type(8))) short bf16x8;
typedef __attribute__((ext_vector_type(4))) float f32x4;

__device__ __forceinline__ unsigned short f2bf(float f) {
    __hip_bfloat16 h = __float2bfloat16(f);
    union { __hip_bfloat16 h; unsigned short u; } cv; cv.h = h; return cv.u;
}

// 64-col bf16 tiles: 128-byte rows, XOR swizzle on byte bits 4-6
__device__ __forceinline__ int swz128(int row, int byte_in_row) {
    return row * 128 + (byte_in_row ^ ((row & 7) << 4));
}

#define MFMA(a, b, c) __builtin_amdgcn_mfma_f32_16x16x32_bf16(a, b, c, 0, 0, 0)

// ---------------- fp32 -> bf16 converters (one-time) ----------------
__global__ __launch_bounds__(256) void cvt8(const float* __restrict__ in,
                                            unsigned short* __restrict__ out, int n8) {
    int i = blockIdx.x * 256 + threadIdx.x;
    if (i >= n8) return;
    const float4* p = (const float4*)in + 2 * (size_t)i;
    float4 a = p[0], b = p[1];
    union { unsigned short s[8]; uint4 v; } u;
    u.s[0] = f2bf(a.x); u.s[1] = f2bf(a.y); u.s[2] = f2bf(a.z); u.s[3] = f2bf(a.w);
    u.s[4] = f2bf(b.x); u.s[5] = f2bf(b.y); u.s[6] = f2bf(b.z); u.s[7] = f2bf(b.w);
    *reinterpret_cast<uint4*>(out + 8 * (size_t)i) = u.v;
}

__global__ __launch_bounds__(256) void cvt8_w(
    const float* __restrict__ W0, const float* __restrict__ W1,
    const float* __restrict__ W2, const float* __restrict__ W3,
    unsigned short* __restrict__ out, int n8) {
    const float* in = (blockIdx.y == 0) ? W0 : (blockIdx.y == 1) ? W1
                    : (blockIdx.y == 2) ? W2 : W3;
    unsigned short* o = out + (size_t)blockIdx.y * n8 * 8;
    int i = blockIdx.x * 256 + threadIdx.x;
    if (i >= n8) return;
    const float4* p = (const float4*)in + 2 * (size_t)i;
    float4 a = p[0], b = p[1];
    union { unsigned short s[8]; uint4 v; } u;
    u.s[0] = f2bf(a.x); u.s[1] = f2bf(a.y); u.s[2] = f2bf(a.z); u.s[3] = f2bf(a.w);
    u.s[4] = f2bf(b.x); u.s[5] = f2bf(b.y); u.s[6] = f2bf(b.z); u.s[7] = f2bf(b.w);
    *reinterpret_cast<uint4*>(o + 8 * (size_t)i) = u.v;
}

// ---------------------------------------------------------------------------
// GEMM: C[M,N] = A[M,K] @ W[N,K]^T, all-bf16 inputs, 128x128 tile, BK=64,
// 4 waves, register-prefetched staging (T14). blockIdx.z picks weight slice.
// ---------------------------------------------------------------------------
template<bool OUT_BF16>
__global__ __launch_bounds__(256) void gemm_mfma(
    const unsigned short* __restrict__ A,
    const unsigned short* __restrict__ Wbase,   // + z*N*K
    void* __restrict__ C0, void* __restrict__ C1, void* __restrict__ C2,
    int M, int N, int K)
{
    const unsigned short* W = Wbase + (size_t)blockIdx.z * N * K;
    void* C = (blockIdx.z == 0) ? C0 : (blockIdx.z == 1) ? C1 : C2;

    __shared__ unsigned short As[128 * 64];
    __shared__ unsigned short Ws[128 * 64];

    const int tid  = threadIdx.x;
    const int m0   = blockIdx.x * 128;
    const int n0   = blockIdx.y * 128;
    const int lane = tid & 63;
    const int wv   = tid >> 6;
    const int wm   = wv >> 1, wn = wv & 1;
    const int g    = lane >> 4;
    const int lr   = lane & 15;
    const int r0   = tid >> 2;
    const int cgrp = tid & 3;

    f32x4 acc[4][4];
#pragma unroll
    for (int i = 0; i < 4; ++i)
#pragma unroll
        for (int j = 0; j < 4; ++j) { f32x4 z = {0.f,0.f,0.f,0.f}; acc[i][j] = z; }

    uint4 pa[2][2], pw[2][2];
    auto issue = [&](int k0) {
#pragma unroll
        for (int rr = 0; rr < 2; ++rr) {
            const unsigned short* sa = A + (size_t)(m0 + r0 + 64 * rr) * K + k0 + cgrp * 16;
            pa[rr][0] = *reinterpret_cast<const uint4*>(sa);
            pa[rr][1] = *reinterpret_cast<const uint4*>(sa + 8);
            const unsigned short* sw = W + (size_t)(n0 + r0 + 64 * rr) * K + k0 + cgrp * 16;
            pw[rr][0] = *reinterpret_cast<const uint4*>(sw);
            pw[rr][1] = *reinterpret_cast<const uint4*>(sw + 8);
        }
    };
    issue(0);

    for (int k0 = 0; k0 < K; k0 += 64) {
        __syncthreads();
#pragma unroll
        for (int rr = 0; rr < 2; ++rr) {
            const int r = r0 + 64 * rr;
            *reinterpret_cast<uint4*>((char*)As + swz128(r, cgrp * 32))      = pa[rr][0];
            *reinterpret_cast<uint4*>((char*)As + swz128(r, cgrp * 32 + 16)) = pa[rr][1];
            *reinterpret_cast<uint4*>((char*)Ws + swz128(r, cgrp * 32))      = pw[rr][0];
            *reinterpret_cast<uint4*>((char*)Ws + swz128(r, cgrp * 32 + 16)) = pw[rr][1];
        }
        __syncthreads();
        if (k0 + 64 < K) issue(k0 + 64);

#pragma unroll
        for (int ks = 0; ks < 2; ++ks) {
            bf16x8 af[4], bfr[4];
#pragma unroll
            for (int i = 0; i < 4; ++i)
                af[i] = *reinterpret_cast<const bf16x8*>(
                    (char*)As + swz128(64 * wm + 16 * i + lr, 64 * ks + 16 * g));
#pragma unroll
            for (int j = 0; j < 4; ++j)
                bfr[j] = *reinterpret_cast<const bf16x8*>(
                    (char*)Ws + swz128(64 * wn + 16 * j + lr, 64 * ks + 16 * g));
#pragma unroll
            for (int i = 0; i < 4; ++i)
#pragma unroll
                for (int j = 0; j < 4; ++j)
                    acc[i][j] = MFMA(af[i], bfr[j], acc[i][j]);
        }
    }

#pragma unroll
    for (int i = 0; i < 4; ++i)
#pragma unroll
        for (int j = 0; j < 4; ++j) {
            const int col = n0 + 64 * wn + 16 * j + lr;
#pragma unroll
            for (int r = 0; r < 4; ++r) {
                const int row = m0 + 64 * wm + 16 * i + 4 * g + r;
                if constexpr (OUT_BF16)
                    ((unsigned short*)C)[(size_t)row * N + col] = f2bf(acc[i][j][r]);
                else
                    ((float*)C)[(size_t)row * N + col] = acc[i][j][r];
            }
        }
}

// ---------------------------------------------------------------------------
// Flash attention, bf16 MFMA, register-prefetched K/V staging, defer-max.
// 4 waves x 64 queries; wave w owns q rows 16w..16w+15; KV tile 64.
// ---------------------------------------------------------------------------
__global__ __launch_bounds__(256) void attn_mfma(
    const unsigned short* __restrict__ Q, const unsigned short* __restrict__ K,
    const unsigned short* __restrict__ V, const int* __restrict__ amask,
    unsigned short* __restrict__ AO)
{
    __shared__ unsigned short Ks[64 * 64];   // [kv][d]  swizzled
    __shared__ unsigned short Vt[64 * 64];   // [d][kv]  swizzled
    __shared__ unsigned short Ps[64 * 64];   // [q][kv]  swizzled
    __shared__ int Ms[64];
    __shared__ int MsBad;

    const int tid = threadIdx.x;
    const int qb  = (int)gridDim.x - 1 - (int)blockIdx.x;   // big blocks first
    const int n0  = qb * 64;
    const int bh  = blockIdx.y;
    const int b = bh >> 3, h = bh & 7;

    const int lane = tid & 63;
    const int wv   = tid >> 6;
    const int g    = lane >> 4;
    const int lr   = lane & 15;

    bf16x8 qf[2];
    {
        const unsigned short* qp =
            Q + (size_t)(b * SEQ + n0 + 16 * wv + lr) * DM + h * DH + 8 * g;
        qf[0] = *reinterpret_cast<const bf16x8*>(qp);
        qf[1] = *reinterpret_cast<const bf16x8*>(qp + 32);
    }

    f32x4 o[4];
#pragma unroll
    for (int j = 0; j < 4; ++j) { f32x4 z = {0.f,0.f,0.f,0.f}; o[j] = z; }
    float m_run[4] = {NEGINF, NEGINF, NEGINF, NEGINF};
    float l_run[4] = {0.f, 0.f, 0.f, 0.f};

    int ntiles = (n0 + 63 + WINDOW - 1) / 64 + 1;
    if (ntiles > SEQ / 64) ntiles = SEQ / 64;

    const int r_st = tid & 63;
    const int half = tid >> 6;

    uint4 kr0, kr1, vr0, vr1; int mr = 1;
    auto issue = [&](int tt) {
        const unsigned short* kp =
            K + (size_t)(b * SEQ + tt * 64 + r_st) * DM + h * DH + 16 * half;
        kr0 = *reinterpret_cast<const uint4*>(kp);
        kr1 = *reinterpret_cast<const uint4*>(kp + 8);
        const unsigned short* vp =
            V + (size_t)(b * SEQ + tt * 64 + r_st) * DM + h * DH + 16 * half;
        vr0 = *reinterpret_cast<const uint4*>(vp);
        vr1 = *reinterpret_cast<const uint4*>(vp + 8);
        if (tid < 64) mr = amask[(size_t)b * SEQ + tt * 64 + tid];
    };
    issue(0);

    for (int t = 0; t < ntiles; ++t) {
        const int kv0 = t * 64;
        __syncthreads();   // previous tile's readers done
        // ---- regs -> LDS ----
        *reinterpret_cast<uint4*>((char*)Ks + swz128(r_st, 32 * half))      = kr0;
        *reinterpret_cast<uint4*>((char*)Ks + swz128(r_st, 32 * half + 16)) = kr1;
        {
            union { uint4 v[2]; unsigned short s[16]; } tv;
            tv.v[0] = vr0; tv.v[1] = vr1;
#pragma unroll
            for (int j = 0; j < 16; ++j)
                *(unsigned short*)((char*)Vt + swz128(16 * half + j, 2 * r_st)) = tv.s[j];
        }
        if (tid < 64) {
            Ms[tid] = mr;
            unsigned long long bad = __ballot(mr == 0);
            if (tid == 0) MsBad = (bad != 0ULL);
        }
        __syncthreads();
        if (t + 1 < ntiles) issue(t + 1);   // prefetch hides under compute

        // waves whose q rows are all below the band skip trailing tiles
        if (kv0 > n0 + 16 * wv + 15 + WINDOW - 1) continue;
        const bool anybad = (MsBad != 0);
        const bool fullband = ((kv0 + 63) <= (n0 + 16 * wv + WINDOW - 1)) && !anybad;

        // ---- S = Q K^T ----
        f32x4 s[4];
#pragma unroll
        for (int f = 0; f < 4; ++f) {
            bf16x8 kf0 = *reinterpret_cast<const bf16x8*>(
                (char*)Ks + swz128(16 * f + lr, 16 * g));
            bf16x8 kf1 = *reinterpret_cast<const bf16x8*>(
                (char*)Ks + swz128(16 * f + lr, 64 + 16 * g));
            f32x4 z = {0.f,0.f,0.f,0.f};
            z = MFMA(qf[0], kf0, z);
            z = MFMA(qf[1], kf1, z);
            s[f] = z;
        }

        // ---- mask (slow path only) + row max (raw units) ----
        float tm[4] = {NEGINF, NEGINF, NEGINF, NEGINF};
        if (fullband) {
#pragma unroll
            for (int f = 0; f < 4; ++f)
#pragma unroll
                for (int r = 0; r < 4; ++r) tm[r] = fmaxf(tm[r], s[f][r]);
        } else {
#pragma unroll
            for (int f = 0; f < 4; ++f)
#pragma unroll
                for (int r = 0; r < 4; ++r) {
                    const int kv = kv0 + 16 * f + lr;
                    const int q  = n0 + 16 * wv + 4 * g + r;
                    const bool ok = ((kv - q) <= (WINDOW - 1)) && (Ms[16 * f + lr] != 0);
                    s[f][r] = ok ? s[f][r] : NEGINF;
                    tm[r] = fmaxf(tm[r], s[f][r]);
                }
        }
#pragma unroll
        for (int r = 0; r < 4; ++r) {
            tm[r] = fmaxf(tm[r], __shfl_xor(tm[r], 1));
            tm[r] = fmaxf(tm[r], __shfl_xor(tm[r], 2));
            tm[r] = fmaxf(tm[r], __shfl_xor(tm[r], 4));
            tm[r] = fmaxf(tm[r], __shfl_xor(tm[r], 8));
            tm[r] *= 0.125f;
        }
        // ---- defer-max rescale (THR=8) ----
        float gg = NEGINF;
#pragma unroll
        for (int r = 0; r < 4; ++r) gg = fmaxf(gg, tm[r] - m_run[r]);
        if (!__all(gg <= 8.f)) {
#pragma unroll
            for (int r = 0; r < 4; ++r) {
                const float mn = fmaxf(m_run[r], tm[r]);
                const float sc = __expf(m_run[r] - mn);
                m_run[r] = mn;
                l_run[r] *= sc;
#pragma unroll
                for (int j = 0; j < 4; ++j) o[j][r] *= sc;
            }
        }
        // ---- P = exp(s*0.125 - m) , accumulate l, stage P ----
        float ls[4] = {0.f, 0.f, 0.f, 0.f};
#pragma unroll
        for (int f = 0; f < 4; ++f)
#pragma unroll
            for (int r = 0; r < 4; ++r) {
                const float p = __expf(fmaf(s[f][r], 0.125f, -m_run[r]));
                ls[r] += p;
                const int row = 16 * wv + 4 * g + r;
                *(unsigned short*)((char*)Ps + swz128(row, 2 * (16 * f + lr))) = f2bf(p);
            }
#pragma unroll
        for (int r = 0; r < 4; ++r) {
            ls[r] += __shfl_xor(ls[r], 1);
            ls[r] += __shfl_xor(ls[r], 2);
            ls[r] += __shfl_xor(ls[r], 4);
            ls[r] += __shfl_xor(ls[r], 8);
            l_run[r] += ls[r];
        }
        // ---- O += P V ----
        bf16x8 pf0 = *reinterpret_cast<const bf16x8*>(
            (char*)Ps + swz128(16 * wv + lr, 16 * g));
        bf16x8 pf1 = *reinterpret_cast<const bf16x8*>(
            (char*)Ps + swz128(16 * wv + lr, 64 + 16 * g));
#pragma unroll
        for (int j = 0; j < 4; ++j) {
            bf16x8 vf0 = *reinterpret_cast<const bf16x8*>(
                (char*)Vt + swz128(16 * j + lr, 16 * g));
            bf16x8 vf1 = *reinterpret_cast<const bf16x8*>(
                (char*)Vt + swz128(16 * j + lr, 64 + 16 * g));
            o[j] = MFMA(pf0, vf0, o[j]);
            o[j] = MFMA(pf1, vf1, o[j]);
        }
    }

    float inv[4];
#pragma unroll
    for (int r = 0; r < 4; ++r) inv[r] = 1.f / l_run[r];
#pragma unroll
    for (int j = 0; j < 4; ++j)
#pragma unroll
        for (int r = 0; r < 4; ++r) {
            const int row = n0 + 16 * wv + 4 * g + r;
            const int col = h * DH + 16 * j + lr;
            AO[(size_t)(b * SEQ + row) * DM + col] = f2bf(o[j][r] * inv[r]);
        }
}

extern "C" void kernel_launch(void* const* d_in, const int* in_sizes, int n_in,
                              void* d_out, int out_size, void* d_ws, size_t ws_size,
                              hipStream_t stream) {
    const float* hs    = (const float*)d_in[0];
    const int*   amask = (const int*)  d_in[1];
    const float* Wq    = (const float*)d_in[2];
    const float* Wk    = (const float*)d_in[3];
    const float* Wv    = (const float*)d_in[4];
    const float* Wo    = (const float*)d_in[5];
    float* out = (float*)d_out;

    const size_t tok = (size_t)BATCH * SEQ * DM;          // 4.19M elems
    const size_t wsz = (size_t)DM * DM;                   // 262144
    unsigned short* hsb = (unsigned short*)d_ws;          // bf16 buffers
    unsigned short* Qb  = hsb + tok;
    unsigned short* Kb  = Qb + tok;
    unsigned short* Vb  = Kb + tok;
    unsigned short* AOb = Vb + tok;
    unsigned short* Wb  = AOb + tok;                      // 4 weights, bf16

    const int M = BATCH * SEQ;   // 8192

    cvt8<<<(int)(tok / 8 / 256), 256, 0, stream>>>(hs, hsb, (int)(tok / 8));
    cvt8_w<<<dim3((int)(wsz / 8 / 256), 4), 256, 0, stream>>>(
        Wq, Wk, Wv, Wo, Wb, (int)(wsz / 8));

    dim3 gQKV(M / 128, DM / 128, 3);
    gemm_mfma<true><<<gQKV, 256, 0, stream>>>(hsb, Wb, Qb, Kb, Vb, M, DM, DM);

    dim3 gAttn(SEQ / 64, BATCH * NH);
    attn_mfma<<<gAttn, 256, 0, stream>>>(Qb, Kb, Vb, amask, AOb);

    dim3 gOut(M / 128, DM / 128, 1);
    gemm_mfma<false><<<gOut, 256, 0, stream>>>(
        AOb, Wb + 3 * wsz, out, out, out, M, DM, DM);
}